// Round 1
// baseline (234.485 us; speedup 1.0000x reference)
//
#include <hip/hip_runtime.h>
#include <hip/hip_bf16.h>
#include <stdint.h>

// Problem constants: N=512, R=4, B=65536, OUT=512
// out = relu(x @ W + b1) @ W2 + b2,  W = krylov_recon(G,H) (512x512)

typedef __attribute__((ext_vector_type(8))) short bf16x8;  // 8 bf16 = 4 VGPRs (MFMA A/B frag)
typedef __attribute__((ext_vector_type(4))) float f32x4;   // MFMA C/D frag

__device__ __forceinline__ unsigned short f2bf(float f) {
  // RNE f32->bf16 via the HIP native conversion (compiler emits v_cvt_pk where possible)
  return __builtin_bit_cast(unsigned short, __float2bfloat16(f));
}

// ---------------------------------------------------------------------------
// Kernel 1: W partials.
// W[a,b] = sum_i sum_j G[(a-j)&511, i] * sgn(b+j) * H[(b+j)&511, i],
// sgn = -1 iff b+j >= 512.  Grid: 64 tiles (64x64) x 4 j-chunks of 128.
// Each thread: 4x4 outputs, G/H staged in LDS as float4 rows (R=4).
// ---------------------------------------------------------------------------
__global__ void build_w_partials(const float* __restrict__ G, const float* __restrict__ H,
                                 float* __restrict__ Wp) {
  __shared__ float4 Gs[512];
  __shared__ float4 Hs[512];
  const int t = threadIdx.x;  // 256
  const float4* G4 = (const float4*)G;
  const float4* H4 = (const float4*)H;
  for (int i = t; i < 512; i += 256) { Gs[i] = G4[i]; Hs[i] = H4[i]; }
  __syncthreads();

  const int blk  = blockIdx.x;      // 0..255
  const int tile = blk >> 2;        // 0..63
  const int jc   = blk & 3;         // j-chunk
  const int a0 = (tile >> 3) << 6;
  const int b0 = (tile & 7) << 6;
  const int ab = a0 + ((t >> 4) << 2);  // 4 consecutive a rows
  const int bb = b0 + ((t & 15) << 2);  // 4 consecutive b cols

  float acc[4][4] = {};
  const int j0 = jc << 7;
  for (int jj = 0; jj < 128; ++jj) {
    const int j = j0 + jj;
    float4 Ga[4], Hb[4];
#pragma unroll
    for (int r = 0; r < 4; ++r) Ga[r] = Gs[(ab + r - j) & 511];
#pragma unroll
    for (int c = 0; c < 4; ++c) {
      const int idx = bb + c + j;                  // < 1024, wraps at most once
      const float s = (idx >= 512) ? -1.f : 1.f;
      const float4 hv = Hs[idx & 511];
      Hb[c].x = hv.x * s; Hb[c].y = hv.y * s; Hb[c].z = hv.z * s; Hb[c].w = hv.w * s;
    }
#pragma unroll
    for (int r = 0; r < 4; ++r)
#pragma unroll
      for (int c = 0; c < 4; ++c)
        acc[r][c] += Ga[r].x * Hb[c].x + Ga[r].y * Hb[c].y +
                     Ga[r].z * Hb[c].z + Ga[r].w * Hb[c].w;
  }

  float* outp = Wp + (size_t)jc * 262144;
#pragma unroll
  for (int r = 0; r < 4; ++r)
#pragma unroll
    for (int c = 0; c < 4; ++c)
      outp[(size_t)(ab + r) * 512 + (bb + c)] = acc[r][c];
}

// ---------------------------------------------------------------------------
// Kernel 2: reduce 4 partials and store W TRANSPOSED as bf16: Wt[n=b][k=a].
// ---------------------------------------------------------------------------
__global__ void reduce_transpose_w(const float* __restrict__ Wp, unsigned short* __restrict__ Wt) {
  const int idx = blockIdx.x * 256 + threadIdx.x;  // 0..262143
  const int b = idx >> 9, a = idx & 511;
  const size_t o = (size_t)a * 512 + b;
  float s = Wp[o] + Wp[o + 262144] + Wp[o + 524288] + Wp[o + 786432];
  Wt[(size_t)b * 512 + a] = f2bf(s);  // coalesced writes over a
}

// ---------------------------------------------------------------------------
// Kernel 3: W2 (512x512 f32, [k][n]) -> W2t bf16 [n][k]
// ---------------------------------------------------------------------------
__global__ void transpose_convert_w2(const float* __restrict__ W2, unsigned short* __restrict__ W2t) {
  const int idx = blockIdx.x * 256 + threadIdx.x;
  const int n = idx >> 9, k = idx & 511;
  W2t[(size_t)n * 512 + k] = f2bf(W2[(size_t)k * 512 + n]);
}

// ---------------------------------------------------------------------------
// Main GEMM: C[M x 512] = epilogue(A[M x 512] @ Bt^T + bias)
//   A_F32:  A is f32 (x), reg-staged with inline f32->bf16 conversion
//   else:   A is bf16 (h), staged via global_load_lds (16B)
//   RELU_BF16: epilogue relu + bf16 store (h);  else f32 store (out)
// 128x128 tile, BK=64, 4 waves (2x2), each wave 64x64 via 4x4 frags of
// 16x16x32 bf16 MFMA. Double-buffered LDS, one barrier per K-step.
// LDS: 2*16KB (A) + 2*16KB (B) = 64KB -> 2 blocks/CU.
// ---------------------------------------------------------------------------
__device__ __forceinline__ void stage16k_lds(const unsigned short* __restrict__ src,
                                             int row0, int kk, short* lbase,
                                             int wid, int lane) {
  // stage a [128][64] bf16 tile (16KB) from row-major src (ld=512) into linear LDS
#pragma unroll
  for (int i = 0; i < 4; ++i) {
    const int c = (wid << 8) + (i << 6) + lane;  // chunk id, 16B each
    const int row = c >> 3, col8 = c & 7;
    const unsigned short* gp = src + (size_t)(row0 + row) * 512 + kk + (col8 << 3);
    short* lp = lbase + (wid << 11) + (i << 9);  // wave-uniform LDS base
    __builtin_amdgcn_global_load_lds((const __attribute__((address_space(1))) void*)gp,
                                     (__attribute__((address_space(3))) void*)lp, 16, 0, 0);
  }
}

template <bool A_F32, bool RELU_BF16>
__global__ __launch_bounds__(256) void mlp_gemm(const void* __restrict__ Ap,
                                                const unsigned short* __restrict__ Bt,
                                                const float* __restrict__ bias,
                                                void* __restrict__ Cp) {
  __shared__ __attribute__((aligned(16))) short As[2][128 * 64];
  __shared__ __attribute__((aligned(16))) short Bs[2][128 * 64];

  // XCD-bijective swizzle (nwg=2048 = 8*256): same-M n-tiles colocate on one XCD
  const int bid = blockIdx.x;
  const int wg  = ((bid & 7) << 8) | (bid >> 3);
  const int m0 = (wg >> 2) << 7;   // 512 M-tiles
  const int n0 = (wg & 3) << 7;    // 4 N-tiles

  const int t = threadIdx.x;
  const int lane = t & 63, wid = t >> 6;
  const int wm = wid >> 1, wn = wid & 1;

  f32x4 acc[4][4];
  const f32x4 vz = {0.f, 0.f, 0.f, 0.f};
#pragma unroll
  for (int i = 0; i < 4; ++i)
#pragma unroll
    for (int j = 0; j < 4; ++j) acc[i][j] = vz;

  float4 areg[8];
  auto loadA = [&](int kk) {  // issue 8 float4 loads of the next x tile
    const float* Af = (const float*)Ap;
#pragma unroll
    for (int i = 0; i < 8; ++i) {
      const int c = t + (i << 8);
      const int row = c >> 4, col4 = c & 15;
      areg[i] = *(const float4*)(Af + (size_t)(m0 + row) * 512 + kk + (col4 << 2));
    }
  };
  auto writeA = [&](int buf) {  // convert + ds_write
#pragma unroll
    for (int i = 0; i < 8; ++i) {
      const int c = t + (i << 8);
      const int row = c >> 4, col4 = c & 15;
      short4 s4;
      s4.x = (short)f2bf(areg[i].x); s4.y = (short)f2bf(areg[i].y);
      s4.z = (short)f2bf(areg[i].z); s4.w = (short)f2bf(areg[i].w);
      *(short4*)&As[buf][row * 64 + (col4 << 2)] = s4;
    }
  };

  auto compute = [&](int buf) {
    const int lr = lane & 15;
    const int lk = (lane >> 4) << 3;
#pragma unroll
    for (int ks = 0; ks < 2; ++ks) {
      bf16x8 af[4], bf_[4];
#pragma unroll
      for (int mi = 0; mi < 4; ++mi)
        af[mi] = *(const bf16x8*)&As[buf][((wm << 6) + (mi << 4) + lr) * 64 + (ks << 5) + lk];
#pragma unroll
      for (int ni = 0; ni < 4; ++ni)
        bf_[ni] = *(const bf16x8*)&Bs[buf][((wn << 6) + (ni << 4) + lr) * 64 + (ks << 5) + lk];
#pragma unroll
      for (int mi = 0; mi < 4; ++mi)
#pragma unroll
        for (int ni = 0; ni < 4; ++ni)
          acc[mi][ni] = __builtin_amdgcn_mfma_f32_16x16x32_bf16(af[mi], bf_[ni], acc[mi][ni], 0, 0, 0);
    }
  };

  // prologue: stage k-step 0 into buf 0
  stage16k_lds(Bt, n0, 0, &Bs[0][0], wid, lane);
  if constexpr (A_F32) { loadA(0); writeA(0); }
  else                 { stage16k_lds((const unsigned short*)Ap, m0, 0, &As[0][0], wid, lane); }
  __syncthreads();  // compiler drains vmcnt/lgkmcnt before s_barrier

  int cur = 0;
  for (int kt = 0; kt < 8; ++kt) {
    const int nxt = cur ^ 1;
    if (kt < 7) {
      stage16k_lds(Bt, n0, (kt + 1) << 6, &Bs[nxt][0], wid, lane);
      if constexpr (A_F32) loadA((kt + 1) << 6);
      else stage16k_lds((const unsigned short*)Ap, m0, (kt + 1) << 6, &As[nxt][0], wid, lane);
    }
    compute(cur);
    if constexpr (A_F32) { if (kt < 7) writeA(nxt); }
    __syncthreads();
    cur = nxt;
  }

  // epilogue: C/D layout col=lane&15, row=(lane>>4)*4+reg   [m89/m91]
  const int cr = (lane >> 4) << 2;
  const int cc = lane & 15;
#pragma unroll
  for (int ni = 0; ni < 4; ++ni) {
    const int gc = n0 + (wn << 6) + (ni << 4) + cc;
    const float bv = bias[gc];
#pragma unroll
    for (int mi = 0; mi < 4; ++mi) {
      const int gr = m0 + (wm << 6) + (mi << 4) + cr;
      const f32x4 v = acc[mi][ni];
#pragma unroll
      for (int r = 0; r < 4; ++r) {
        float val = v[r] + bv;
        if constexpr (RELU_BF16) {
          val = val > 0.f ? val : 0.f;
          ((unsigned short*)Cp)[(size_t)(gr + r) * 512 + gc] = f2bf(val);
        } else {
          ((float*)Cp)[(size_t)(gr + r) * 512 + gc] = val;
        }
      }
    }
  }
}

// ---------------------------------------------------------------------------
extern "C" void kernel_launch(void* const* d_in, const int* in_sizes, int n_in,
                              void* d_out, int out_size, void* d_ws, size_t ws_size,
                              hipStream_t stream) {
  (void)in_sizes; (void)n_in; (void)out_size; (void)ws_size;
  const float* x  = (const float*)d_in[0];  // (65536, 512)
  const float* G  = (const float*)d_in[1];  // (512, 4)
  const float* H  = (const float*)d_in[2];  // (512, 4)
  const float* b1 = (const float*)d_in[3];  // (512,)
  const float* W2 = (const float*)d_in[4];  // (512, 512)
  const float* b2 = (const float*)d_in[5];  // (512,)
  float* out = (float*)d_out;               // (65536, 512) f32

  // workspace layout (needs ~72.4 MB)
  char* ws = (char*)d_ws;
  unsigned short* h   = (unsigned short*)ws;                 // 67,108,864 B (bf16 hidden)
  unsigned short* Wt  = (unsigned short*)(ws + 67108864);    //    524,288 B
  unsigned short* W2t = (unsigned short*)(ws + 67633152);    //    524,288 B
  float*          Wp  = (float*)(ws + 68157440);             //  4,194,304 B

  build_w_partials<<<256, 256, 0, stream>>>(G, H, Wp);
  reduce_transpose_w<<<1024, 256, 0, stream>>>(Wp, Wt);
  transpose_convert_w2<<<1024, 256, 0, stream>>>(W2, W2t);
  mlp_gemm<true, true><<<2048, 256, 0, stream>>>((const void*)x, Wt, b1, (void*)h);
  mlp_gemm<false, false><<<2048, 256, 0, stream>>>((const void*)h, W2t, b2, (void*)out);
}

// Round 2
// 166.579 us; speedup vs baseline: 1.4076x; 1.4076x over previous
//
#include <hip/hip_runtime.h>
#include <hip/hip_bf16.h>
#include <stdint.h>

// Problem: N=512, R=4, B=65536, OUT=512
// out = relu(x @ W + b1) @ W2 + b2,  W = krylov_recon(G,H) (512x512)

typedef __attribute__((ext_vector_type(8))) short bf16x8;       // MFMA A/B frag (4 VGPR)
typedef __attribute__((ext_vector_type(4))) float f32x4;        // MFMA C/D frag
typedef __attribute__((ext_vector_type(4))) unsigned int u32x4;

__device__ __forceinline__ unsigned short f2bf(float f) {
  return __builtin_bit_cast(unsigned short, __float2bfloat16(f));
}

// ---------------------------------------------------------------------------
// Kernel 1: W partials.  W[a,b] = sum_i sum_j G[(a-j)&511,i]*sgn(b+j)*H[(b+j)&511,i]
// ---------------------------------------------------------------------------
__global__ void build_w_partials(const float* __restrict__ G, const float* __restrict__ H,
                                 float* __restrict__ Wp) {
  __shared__ float4 Gs[512];
  __shared__ float4 Hs[512];
  const int t = threadIdx.x;  // 256
  const float4* G4 = (const float4*)G;
  const float4* H4 = (const float4*)H;
  for (int i = t; i < 512; i += 256) { Gs[i] = G4[i]; Hs[i] = H4[i]; }
  __syncthreads();

  const int blk  = blockIdx.x;      // 0..255
  const int tile = blk >> 2;
  const int jc   = blk & 3;
  const int a0 = (tile >> 3) << 6;
  const int b0 = (tile & 7) << 6;
  const int ab = a0 + ((t >> 4) << 2);
  const int bb = b0 + ((t & 15) << 2);

  float acc[4][4] = {};
  const int j0 = jc << 7;
  for (int jj = 0; jj < 128; ++jj) {
    const int j = j0 + jj;
    float4 Ga[4], Hb[4];
#pragma unroll
    for (int r = 0; r < 4; ++r) Ga[r] = Gs[(ab + r - j) & 511];
#pragma unroll
    for (int c = 0; c < 4; ++c) {
      const int idx = bb + c + j;
      const float s = (idx >= 512) ? -1.f : 1.f;
      const float4 hv = Hs[idx & 511];
      Hb[c].x = hv.x * s; Hb[c].y = hv.y * s; Hb[c].z = hv.z * s; Hb[c].w = hv.w * s;
    }
#pragma unroll
    for (int r = 0; r < 4; ++r)
#pragma unroll
      for (int c = 0; c < 4; ++c)
        acc[r][c] += Ga[r].x * Hb[c].x + Ga[r].y * Hb[c].y +
                     Ga[r].z * Hb[c].z + Ga[r].w * Hb[c].w;
  }

  float* outp = Wp + (size_t)jc * 262144;
#pragma unroll
  for (int r = 0; r < 4; ++r)
#pragma unroll
    for (int c = 0; c < 4; ++c)
      outp[(size_t)(ab + r) * 512 + (bb + c)] = acc[r][c];
}

// ---------------------------------------------------------------------------
// Kernel 2: reduce 4 partials, store W transposed bf16: Wt[n=b][k=a]
// ---------------------------------------------------------------------------
__global__ void reduce_transpose_w(const float* __restrict__ Wp, unsigned short* __restrict__ Wt) {
  const int idx = blockIdx.x * 256 + threadIdx.x;
  const int b = idx >> 9, a = idx & 511;
  const size_t o = (size_t)a * 512 + b;
  float s = Wp[o] + Wp[o + 262144] + Wp[o + 524288] + Wp[o + 786432];
  Wt[(size_t)b * 512 + a] = f2bf(s);
}

// ---------------------------------------------------------------------------
// Kernel 3: W2 (512x512 f32 [k][n]) -> W2t bf16 [n][k]
// ---------------------------------------------------------------------------
__global__ void transpose_convert_w2(const float* __restrict__ W2, unsigned short* __restrict__ W2t) {
  const int idx = blockIdx.x * 256 + threadIdx.x;
  const int n = idx >> 9, k = idx & 511;
  W2t[(size_t)n * 512 + k] = f2bf(W2[(size_t)k * 512 + n]);
}

// ---------------------------------------------------------------------------
// Pipelined GEMM: C[M x 512] = epi(A[M x 512] @ Bt^T + bias)
// BM=128, BN=512, BK=32, nt=16 K-tiles. 8 waves (WM=2 x WN=4), per-wave 64x128.
// 3-slot LDS ring, prefetch distance 2, one counted vmcnt per K-tile.
// A_F32: A staged as raw f32 (gll), converted in-reg via v_cvt_pk_bf16_f32 (RNE);
//        epilogue relu + bf16 store.  else: A bf16 gll; epilogue f32 store.
// LDS tiles XOR-swizzled; gll writes linear LDS, so the *global source* is
// pre-swizzled per 16B chunk (rule 21) and ds_read applies the same XOR.
// ---------------------------------------------------------------------------
template <bool A_F32>
__global__ __launch_bounds__(512, 2) void mlp_gemm_pipe(
    const void* __restrict__ Ap, const unsigned short* __restrict__ Bt,
    const float* __restrict__ bias, void* __restrict__ Cp) {
  constexpr int AB  = A_F32 ? 16384 : 8192;   // A tile bytes (128 x 32 x {4,2}B)
  constexpr int BB  = 32768;                  // B tile bytes (512 x 32 x 2B)
  constexpr int NT  = 16;                     // K tiles
  constexpr int NAG = A_F32 ? 2 : 1;          // A glls / thread / tile

  __shared__ __attribute__((aligned(16))) char lds[3 * (AB + BB)];

  const int tid  = threadIdx.x;
  const int lane = tid & 63;
  const int w    = tid >> 6;      // 0..7
  const int wm   = w & 1;         // 2 M groups of 64 rows
  const int wn   = w >> 1;        // 4 N groups of 128 cols
  const int m0   = (int)blockIdx.x << 7;

  // ---- stage source pointers (pre-swizzled global columns) ----
  const char* aSrc[NAG];
  int aDst[NAG];
  if constexpr (A_F32) {
    const float* Af = (const float*)Ap;
#pragma unroll
    for (int i = 0; i < 2; ++i) {
      const int c = (w * 2 + i) * 64 + lane;   // 16B chunk id, 1024 total
      const int row = c >> 3, sl = c & 7;      // 8 slots per 128B f32 row
      aSrc[i] = (const char*)(Af + (size_t)(m0 + row) * 512 + ((sl ^ (row & 7)) << 2));
      aDst[i] = (w * 2 + i) * 1024;
    }
  } else {
    const unsigned short* Ab = (const unsigned short*)Ap;
    const int c = w * 64 + lane;               // 512 chunks
    const int row = c >> 2, sl = c & 3;        // 4 slots per 64B bf16 row
    aSrc[0] = (const char*)(Ab + (size_t)(m0 + row) * 512 + ((sl ^ (row & 3)) << 3));
    aDst[0] = w * 1024;
  }
  const char* bSrc[4];
  int bDst[4];
#pragma unroll
  for (int i = 0; i < 4; ++i) {
    const int c = (w * 4 + i) * 64 + lane;     // 2048 chunks (512 n-rows)
    const int row = c >> 2, sl = c & 3;
    bSrc[i] = (const char*)(Bt + (size_t)row * 512 + ((sl ^ (row & 3)) << 3));
    bDst[i] = (w * 4 + i) * 1024;
  }

  auto stageA = [&](int kt, int slot) {
#pragma unroll
    for (int i = 0; i < NAG; ++i)
      __builtin_amdgcn_global_load_lds(
        (const __attribute__((address_space(1))) void*)(aSrc[i] + (kt << (A_F32 ? 7 : 6))),
        (__attribute__((address_space(3))) void*)(lds + slot * AB + aDst[i]), 16, 0, 0);
  };
  auto stageB = [&](int kt, int slot) {
#pragma unroll
    for (int i = 0; i < 4; ++i)
      __builtin_amdgcn_global_load_lds(
        (const __attribute__((address_space(1))) void*)(bSrc[i] + (kt << 6)),
        (__attribute__((address_space(3))) void*)(lds + 3 * AB + slot * BB + bDst[i]), 16, 0, 0);
  };

  // ---- swizzled ds_read byte offsets ----
  int offA[4][2];
#pragma unroll
  for (int mi = 0; mi < 4; ++mi) {
    const int r = wm * 64 + mi * 16 + (lane & 15);
    if constexpr (A_F32) {
#pragma unroll
      for (int j = 0; j < 2; ++j)
        offA[mi][j] = r * 128 + (((((lane >> 4) << 1) + j) ^ (r & 7)) << 4);
    } else {
      offA[mi][0] = r * 64 + (((lane >> 4) ^ (r & 3)) << 4);
      offA[mi][1] = 0;
    }
  }
  int offB[8];
#pragma unroll
  for (int ng = 0; ng < 8; ++ng) {
    const int r = wn * 128 + ng * 16 + (lane & 15);
    offB[ng] = r * 64 + (((lane >> 4) ^ (r & 3)) << 4);
  }

  f32x4 acc[4][8];
  const f32x4 vz = {0.f, 0.f, 0.f, 0.f};
#pragma unroll
  for (int i = 0; i < 4; ++i)
#pragma unroll
    for (int j = 0; j < 8; ++j) acc[i][j] = vz;

  // ---- prologue: tiles 0,1 in flight; wait tile 0 ----
  stageA(0, 0); stageB(0, 0);
  stageA(1, 1); stageB(1, 1);
  if constexpr (A_F32) asm volatile("s_waitcnt vmcnt(6)" ::: "memory");
  else                 asm volatile("s_waitcnt vmcnt(5)" ::: "memory");
  __builtin_amdgcn_s_barrier();
  __builtin_amdgcn_sched_barrier(0);

  bf16x8 afr[4];
#pragma unroll
  for (int kt = 0; kt < NT; ++kt) {
    const int sl  = kt % 3;
    const int sl2 = (kt + 2) % 3;   // ring slot of tile kt-1, fully consumed
    const char* aS = lds + sl * AB;
    const char* bS = lds + 3 * AB + sl * BB;

    // ---------- phase 0: A frags + B ng0-3, stage A(kt+2), MFMA quad 0 ----------
    {
      bf16x8 bfr[4];
#pragma unroll
      for (int g = 0; g < 4; ++g) bfr[g] = *(const bf16x8*)(bS + offB[g]);
      f32x4 lo[4], hi[4];
      if constexpr (A_F32) {
#pragma unroll
        for (int mi = 0; mi < 4; ++mi) {
          lo[mi] = *(const f32x4*)(aS + offA[mi][0]);
          hi[mi] = *(const f32x4*)(aS + offA[mi][1]);
        }
      } else {
#pragma unroll
        for (int mi = 0; mi < 4; ++mi) afr[mi] = *(const bf16x8*)(aS + offA[mi][0]);
      }
      if (kt + 2 < NT) stageA(kt + 2, sl2);
      __builtin_amdgcn_s_barrier();
      asm volatile("s_waitcnt lgkmcnt(0)" ::: "memory");
      __builtin_amdgcn_sched_barrier(0);
      if constexpr (A_F32) {
#pragma unroll
        for (int mi = 0; mi < 4; ++mi) {   // RNE f32->bf16 pack
          unsigned int w0, w1, w2, w3;
          asm("v_cvt_pk_bf16_f32 %0, %1, %2" : "=v"(w0) : "v"(lo[mi].x), "v"(lo[mi].y));
          asm("v_cvt_pk_bf16_f32 %0, %1, %2" : "=v"(w1) : "v"(lo[mi].z), "v"(lo[mi].w));
          asm("v_cvt_pk_bf16_f32 %0, %1, %2" : "=v"(w2) : "v"(hi[mi].x), "v"(hi[mi].y));
          asm("v_cvt_pk_bf16_f32 %0, %1, %2" : "=v"(w3) : "v"(hi[mi].z), "v"(hi[mi].w));
          u32x4 pw = {w0, w1, w2, w3};
          afr[mi] = __builtin_bit_cast(bf16x8, pw);
        }
      }
      __builtin_amdgcn_s_setprio(1);
#pragma unroll
      for (int mi = 0; mi < 4; ++mi)
#pragma unroll
        for (int g = 0; g < 4; ++g)
          acc[mi][g] = __builtin_amdgcn_mfma_f32_16x16x32_bf16(afr[mi], bfr[g], acc[mi][g], 0, 0, 0);
      __builtin_amdgcn_s_setprio(0);
      __builtin_amdgcn_s_barrier();
      __builtin_amdgcn_sched_barrier(0);
    }

    // ---------- phase 1: B ng4-7, stage B(kt+2), MFMA quad 1, boundary vmcnt ----------
    {
      bf16x8 bfr[4];
#pragma unroll
      for (int g = 0; g < 4; ++g) bfr[g] = *(const bf16x8*)(bS + offB[4 + g]);
      if (kt + 2 < NT) stageB(kt + 2, sl2);
      __builtin_amdgcn_s_barrier();
      asm volatile("s_waitcnt lgkmcnt(0)" ::: "memory");
      __builtin_amdgcn_sched_barrier(0);
      __builtin_amdgcn_s_setprio(1);
#pragma unroll
      for (int mi = 0; mi < 4; ++mi)
#pragma unroll
        for (int g = 0; g < 4; ++g)
          acc[mi][4 + g] = __builtin_amdgcn_mfma_f32_16x16x32_bf16(afr[mi], bfr[g], acc[mi][4 + g], 0, 0, 0);
      __builtin_amdgcn_s_setprio(0);
      if (kt < NT - 2) {          // ensure tile kt+1 fully landed; keep kt+2 in flight
        if constexpr (A_F32) asm volatile("s_waitcnt vmcnt(6)" ::: "memory");
        else                 asm volatile("s_waitcnt vmcnt(5)" ::: "memory");
      } else if (kt == NT - 2) {
        asm volatile("s_waitcnt vmcnt(0)" ::: "memory");
      }
      __builtin_amdgcn_s_barrier();
      __builtin_amdgcn_sched_barrier(0);
    }
  }

  // ---- epilogue: C/D layout col=lane&15, row=(lane>>4)*4+reg ----
  const int cr = (lane >> 4) << 2;
  const int cc = lane & 15;
#pragma unroll
  for (int ng = 0; ng < 8; ++ng) {
    const int gc = wn * 128 + ng * 16 + cc;
    const float bv = bias[gc];
#pragma unroll
    for (int mi = 0; mi < 4; ++mi) {
      const int gr = m0 + wm * 64 + mi * 16 + cr;
      const f32x4 v = acc[mi][ng];
#pragma unroll
      for (int r = 0; r < 4; ++r) {
        const float val = v[r] + bv;
        if constexpr (A_F32)
          ((unsigned short*)Cp)[(size_t)(gr + r) * 512 + gc] = f2bf(val > 0.f ? val : 0.f);
        else
          ((float*)Cp)[(size_t)(gr + r) * 512 + gc] = val;
      }
    }
  }
}

// ---------------------------------------------------------------------------
extern "C" void kernel_launch(void* const* d_in, const int* in_sizes, int n_in,
                              void* d_out, int out_size, void* d_ws, size_t ws_size,
                              hipStream_t stream) {
  (void)in_sizes; (void)n_in; (void)out_size; (void)ws_size;
  const float* x  = (const float*)d_in[0];  // (65536, 512)
  const float* G  = (const float*)d_in[1];  // (512, 4)
  const float* H  = (const float*)d_in[2];  // (512, 4)
  const float* b1 = (const float*)d_in[3];  // (512,)
  const float* W2 = (const float*)d_in[4];  // (512, 512)
  const float* b2 = (const float*)d_in[5];  // (512,)
  float* out = (float*)d_out;               // (65536, 512) f32

  char* ws = (char*)d_ws;                                    // ~72.4 MB
  unsigned short* h   = (unsigned short*)ws;                 // 67,108,864 B
  unsigned short* Wt  = (unsigned short*)(ws + 67108864);    //    524,288 B
  unsigned short* W2t = (unsigned short*)(ws + 67633152);    //    524,288 B
  float*          Wp  = (float*)(ws + 68157440);             //  4,194,304 B

  build_w_partials<<<256, 256, 0, stream>>>(G, H, Wp);
  reduce_transpose_w<<<1024, 256, 0, stream>>>(Wp, Wt);
  transpose_convert_w2<<<1024, 256, 0, stream>>>(W2, W2t);
  mlp_gemm_pipe<true><<<512, 512, 0, stream>>>((const void*)x, Wt, b1, (void*)h);
  mlp_gemm_pipe<false><<<512, 512, 0, stream>>>((const void*)h, W2t, b2, (void*)out);
}